// Round 1
// baseline (446.247 us; speedup 1.0000x reference)
//
#include <hip/hip_runtime.h>
#include <stdint.h>

#define T_SEQ 4096
#define HID   2048
#define NH    16
#define HD    128

typedef __attribute__((ext_vector_type(8))) short short8;
typedef __attribute__((ext_vector_type(4))) short short4v;
typedef __attribute__((ext_vector_type(4))) float f32x4;

typedef __attribute__((address_space(1))) void as1_void;
typedef __attribute__((address_space(3))) void as3_void;

__device__ __forceinline__ unsigned short f2bf(float f){
  unsigned u = __builtin_bit_cast(unsigned, f);
  u += 0x7fffu + ((u >> 16) & 1u);
  return (unsigned short)(u >> 16);
}
__device__ __forceinline__ float bf2f(unsigned short b){
  unsigned u = ((unsigned)b) << 16;
  return __builtin_bit_cast(float, u);
}
// async global->LDS, 16B per lane. LDS side is wave-uniform base + lane*16.
__device__ __forceinline__ void gll16(const void* g, void* l){
  __builtin_amdgcn_global_load_lds((as1_void*)(uintptr_t)g,
                                   (as3_void*)(unsigned)(uintptr_t)l, 16, 0, 0);
}

// counted waits + raw barrier (T3/T4 pattern: never drain vmcnt to 0 mid-loop)
#define VM_WAIT(N)  asm volatile("s_waitcnt vmcnt(" #N ")" ::: "memory")
#define LGKM_WAIT0  asm volatile("s_waitcnt lgkmcnt(0)" ::: "memory")
__device__ __forceinline__ void barrier_fence(){
  asm volatile("" ::: "memory");
  __builtin_amdgcn_s_barrier();
  asm volatile("" ::: "memory");
}

// ---------------- fp32 -> bf16 conversion of X ----------------
__global__ __launch_bounds__(256) void conv_x_k(const float* __restrict__ X,
                                                unsigned short* __restrict__ O){
  int i = (blockIdx.x * 256 + threadIdx.x) * 4;
  float4 v = *(const float4*)(X + i);
  short4v o;
  o[0] = (short)f2bf(v.x); o[1] = (short)f2bf(v.y);
  o[2] = (short)f2bf(v.z); o[3] = (short)f2bf(v.w);
  *(short4v*)(O + i) = o;
}

// ------------- weight transpose + bf16: W[k][n] -> Wt[n][k] -------------
__global__ __launch_bounds__(256) void conv_wt_k(const float* __restrict__ W0,
                                                 const float* __restrict__ W1,
                                                 const float* __restrict__ W2,
                                                 const float* __restrict__ W3,
                                                 unsigned short* __restrict__ Wt){
  const float* W = (blockIdx.z == 0) ? W0 : (blockIdx.z == 1) ? W1
                   : (blockIdx.z == 2) ? W2 : W3;
  unsigned short* out = Wt + (size_t)blockIdx.z * HID * HID;
  __shared__ float tile[32][33];
  const int x = threadIdx.x;       // 0..31
  const int y = threadIdx.y;       // 0..7
  const int k0 = blockIdx.y * 32, n0 = blockIdx.x * 32;
#pragma unroll
  for (int i = 0; i < 4; ++i){
    int r = y * 4 + i;
    tile[r][x] = W[(size_t)(k0 + r) * HID + n0 + x];
  }
  __syncthreads();
#pragma unroll
  for (int i = 0; i < 4; ++i){
    int r = y * 4 + i;
    out[(size_t)(n0 + r) * HID + k0 + x] = f2bf(tile[x][r]);
  }
}

// ---------------- GEMM: C[M][N] = A[M][K=2048] * Bt[N][K]^T ----------------
// 128x128 tile, 4 waves (2x2), BK=64 (32 iters), global_load_lds(16B).
// LDS slot (row, c) holds global chunk c ^ (row&7); fragment read chunk
// (ks*4+qd) ^ (mm&7) -> bank-uniform.
// MODE 0: epilogue scatters bf16 to Q [h][t][d], K [h][t][d], Vt [h][d][t].
// MODE 1: epilogue writes fp32 C row-major [M][NTOT].
template<int MODE, int NTOT>
__global__ __launch_bounds__(256, 3) void gemm_bt(
    const unsigned short* __restrict__ A,
    const unsigned short* __restrict__ Bt,
    unsigned short* __restrict__ Qb,
    unsigned short* __restrict__ Kb,
    unsigned short* __restrict__ Vt,
    float* __restrict__ Cf)
{
  constexpr int K = HID;
  __shared__ __align__(16) unsigned short lA[128 * 64];
  __shared__ __align__(16) unsigned short lB[128 * 64];

  const int tid  = threadIdx.x;
  const int wave = tid >> 6;
  const int lane = tid & 63;
  const int qd   = lane >> 4;
  const int mm   = lane & 15;
  const int m7   = mm & 7;
  const int wm   = wave >> 1;
  const int wn   = wave & 1;
  const int bm   = blockIdx.y * 128;
  const int bn   = blockIdx.x * 128;

  const unsigned short* ga[4];
  const unsigned short* gb[4];
  unsigned short* la[4];
  unsigned short* lbp[4];
#pragma unroll
  for (int i = 0; i < 4; ++i){
    int s0   = (wave * 4 + i) * 64;   // wave-uniform base slot
    int slot = s0 + lane;
    int row  = slot >> 3;
    int kb   = (slot & 7) ^ (row & 7);
    ga[i]  = A  + (size_t)(bm + row) * K + kb * 8;
    gb[i]  = Bt + (size_t)(bn + row) * K + kb * 8;
    la[i]  = lA + s0 * 8;
    lbp[i] = lB + s0 * 8;
  }

  int abase[4], bbase[4];
#pragma unroll
  for (int t = 0; t < 4; ++t){
    abase[t] = (wm * 64 + t * 16 + mm) * 8;
    bbase[t] = (wn * 64 + t * 16 + mm) * 8;
  }

  const f32x4 fzero = {0.f, 0.f, 0.f, 0.f};
  f32x4 acc[4][4];
#pragma unroll
  for (int i = 0; i < 4; ++i)
#pragma unroll
    for (int j = 0; j < 4; ++j) acc[i][j] = fzero;

  for (int k0 = 0; k0 < K; k0 += 64){
    __syncthreads();
#pragma unroll
    for (int i = 0; i < 4; ++i){
      gll16(ga[i] + k0, la[i]);
      gll16(gb[i] + k0, lbp[i]);
    }
    __syncthreads();
#pragma unroll
    for (int ks = 0; ks < 2; ++ks){
      const int co = (ks * 4 + qd) ^ m7;
      short8 af[4], bfv[4];
#pragma unroll
      for (int t = 0; t < 4; ++t) af[t]  = *(const short8*)(lA + (abase[t] + co) * 8);
#pragma unroll
      for (int t = 0; t < 4; ++t) bfv[t] = *(const short8*)(lB + (bbase[t] + co) * 8);
#pragma unroll
      for (int i = 0; i < 4; ++i)
#pragma unroll
        for (int j = 0; j < 4; ++j)
          acc[i][j] = __builtin_amdgcn_mfma_f32_16x16x32_bf16(af[i], bfv[j], acc[i][j], 0, 0, 0);
    }
  }

#pragma unroll
  for (int i = 0; i < 4; ++i){
#pragma unroll
    for (int j = 0; j < 4; ++j){
      const int col = bn + wn * 64 + j * 16 + mm;
#pragma unroll
      for (int r = 0; r < 4; ++r){
        const int row = bm + wm * 64 + i * 16 + qd * 4 + r;
        const float v = acc[i][j][r];
        if (MODE == 0){
          const int sel = col >> 11;
          const int nn  = col & 2047;
          const int h   = nn >> 7;
          const int d   = nn & 127;
          const unsigned short bv = f2bf(v);
          if (sel == 0)      Qb[((size_t)h * T_SEQ + row) * HD + d] = bv;
          else if (sel == 1) Kb[((size_t)h * T_SEQ + row) * HD + d] = bv;
          else               Vt[((size_t)(h * HD + d)) * T_SEQ + row] = bv;
        } else {
          Cf[(size_t)row * NTOT + col] = v;
        }
      }
    }
  }
}

// ---------------- RoPE on Q and K (in place, bf16) ----------------
__global__ __launch_bounds__(256) void rope_k(unsigned short* __restrict__ Qb,
                                              unsigned short* __restrict__ Kb){
  const int j = threadIdx.x & 63;
  const int t = blockIdx.x * 4 + (threadIdx.x >> 6);
  const int h = blockIdx.y;
  const float fr = (float)t * __expf(-(float)j * (9.210340371976184f / 64.f));
  const float cs = cosf(fr), sn = sinf(fr);
  const size_t base = ((size_t)h * T_SEQ + t) * HD;
  {
    float x1 = bf2f(Qb[base + j]), x2 = bf2f(Qb[base + j + 64]);
    Qb[base + j]      = f2bf(x1 * cs - x2 * sn);
    Qb[base + j + 64] = f2bf(x2 * cs + x1 * sn);
  }
  {
    float x1 = bf2f(Kb[base + j]), x2 = bf2f(Kb[base + j + 64]);
    Kb[base + j]      = f2bf(x1 * cs - x2 * sn);
    Kb[base + j + 64] = f2bf(x2 * cs + x1 * sn);
  }
}

// ---------------- flash attention v6 (pipelined staging) ----------------
// Block = 4 waves = 2 row-groups (rg, 32 q-rows) x 2 key-groups (kg, 32 keys).
// Block q-tile = 64 rows; paired tiles (p, 63-p) -> 65 iters total, grid 512
// = exactly 2 blocks/CU.
// v6 vs v5: K double-buffered in LDS, V single-buffered; K(it+1) issued at
// iter top, V(it+1) issued after the post-PV barrier. Raw s_barrier with
// COUNTED vmcnt (8 / 4 / 0-only-on-last-iter) instead of __syncthreads'
// vmcnt(0) drain -> staging latency hides under a full iteration of compute.
// Wait ledger (per wave, 4 K + 4 V loads/iter, order K(it),V(it),K(it+1)):
//   consume K(it): newer = V(it)+K(it+1) = 8  -> vmcnt(8)  [4 on last iter]
//   consume V(it): newer = K(it+1)       = 4  -> vmcnt(4)  [0 on last iter]
// lgkmcnt(0) before the post-PV barrier: all lV/lK ds_reads must complete
// before any wave's V(it+1)/K(it+2) global_load_lds writes can land (WAR).
// LDS 57600 B (2x16K K + 16K V + 8K P + lL) -> x2 blocks = 115 KB < 160 KB.
// T5: s_setprio(1) around both MFMA clusters (stage-issuing vs MFMA waves).
__global__ __launch_bounds__(256, 2) void attn_k(
    const unsigned short* __restrict__ Qb,   // [NH][T][HD]
    const unsigned short* __restrict__ Kb,   // [NH][T][HD]
    const unsigned short* __restrict__ Vt,   // [NH][HD][T]
    unsigned short* __restrict__ Yb)         // [T][HID]
{
  __shared__ __align__(16) unsigned char smem[57600];
  unsigned short* lK = (unsigned short*)smem;              // 2 x [64 keys][128 d] 32 KB
  unsigned short* lV = (unsigned short*)(smem + 32768);    // [128 d][64 keys]     16 KB
  unsigned short (*lP)[32][32] = (unsigned short(*)[32][32])(smem + 49152); // 8 KB
  float* lL = (float*)(smem + 57344);                      // [64]
  float* lO = (float*)smem;                                // [128 d][68] epilogue overlay

  const int tid  = threadIdx.x;
  const int w    = tid >> 6;
  const int rg   = w >> 1;
  const int kg   = w & 1;
  const int lane = tid & 63;
  const int qd   = lane >> 4;
  const int cc   = lane & 15;
  const int cx   = cc & 7;
  const int r8   = lane >> 3, c7 = lane & 7;

  const int b = blockIdx.x;                 // 512 blocks
  const int h = (b & 7) + 8 * (b >> 8);     // head -> XCD h&7 (L2 locality)
  const int pairP = (b >> 3) & 31;          // 0..31

  // staging source addressing (swizzle on fetch side; slot chunk c holds
  // global chunk c ^ (row&7))
  const int ce  = cc ^ qd;
  const int dlt = (ce & 4) ? -32 : 32;
  const unsigned short* gKbp = Kb + ((size_t)h * T_SEQ + w * 16 + qd) * HD + ce * 8;
  const int cV = c7 ^ r8;
  const unsigned short* gVbp = Vt + ((size_t)h * HD + w * 32 + r8) * T_SEQ + cV * 8;

  const f32x4 fzero = {0.f, 0.f, 0.f, 0.f};
  // 50*tanh(s*SCALE/50) ~= s*(A0 + A1*s^2 + A2*s^4)
  const float A0 = 0.0625f;
  const float A1 = -3.2552083e-8f;
  const float A2 = 2.0345052e-14f;

#pragma unroll 1
  for (int half = 0; half < 2; ++half){
    const int tp = half ? (63 - pairP) : pairP;
    const int qrow0 = tp * 64 + rg * 32;
    const int iters = tp + 1;

    // prologue: stage K(0) -> buffer 0, V(0) -> lV (4+4 loads per wave)
    {
      unsigned short* dK = lK + w * 2048;
#pragma unroll
      for (int i = 0; i < 4; ++i)
        gll16(gKbp + (size_t)(i * 4) * HD + ((i & 1) ? dlt : 0), dK + i * 512);
      unsigned short* dV = lV + w * 2048;
#pragma unroll
      for (int i = 0; i < 4; ++i)
        gll16(gVbp + (size_t)i * 8 * T_SEQ, dV + i * 512);
    }

    // Q fragments: A-layout, rows qrow0 + mt*16 + cc, d = ks*32 + qd*8
    short8 qf[2][4];
#pragma unroll
    for (int mt = 0; mt < 2; ++mt)
#pragma unroll
      for (int ks = 0; ks < 4; ++ks)
        qf[mt][ks] = *(const short8*)(Qb + ((size_t)h * T_SEQ + qrow0 + mt * 16 + cc) * HD + ks * 32 + qd * 8);

    f32x4 o[2][8];
    float lsum[2][4];
#pragma unroll
    for (int mt = 0; mt < 2; ++mt){
#pragma unroll
      for (int dn = 0; dn < 8; ++dn) o[mt][dn] = fzero;
#pragma unroll
      for (int r = 0; r < 4; ++r) lsum[mt][r] = 0.f;
    }

    int curo = 0;   // current K buffer offset in shorts (0 or 8192)
#pragma unroll 1
    for (int it = 0; it < iters; ++it){
      const int k0 = it * 64;

      // prefetch K(it+1) into the other buffer, then counted wait for K(it)
      if (it + 1 < iters){
        const unsigned short* gK = gKbp + (size_t)(k0 + 64) * HD;
        unsigned short* dK = lK + (curo ^ 8192) + w * 2048;
#pragma unroll
        for (int i = 0; i < 4; ++i)
          gll16(gK + (size_t)(i * 4) * HD + ((i & 1) ? dlt : 0), dK + i * 512);
        VM_WAIT(8);      // retire K(it); V(it)+K(it+1) stay in flight
      } else {
        VM_WAIT(4);      // retire K(it); V(it) stays in flight
      }
      barrier_fence();   // all waves' K(it) landed; lK[curo] valid

      const unsigned short* lKc = lK + curo;

      // S = Q K^T : wave's keys = k0 + kg*32 + nt*16 + cc (nt=0..1)
      f32x4 S[2][2];
#pragma unroll
      for (int mt = 0; mt < 2; ++mt)
#pragma unroll
        for (int nt = 0; nt < 2; ++nt) S[mt][nt] = fzero;
      __builtin_amdgcn_s_setprio(1);
#pragma unroll
      for (int nt = 0; nt < 2; ++nt){
        short8 kf[4];
#pragma unroll
        for (int ks = 0; ks < 4; ++ks)
          kf[ks] = *(const short8*)(lKc + ((kg * 32 + nt * 16 + cc) * 16 + ((ks * 4 + qd) ^ cx)) * 8);
#pragma unroll
        for (int mt = 0; mt < 2; ++mt)
#pragma unroll
          for (int ks = 0; ks < 4; ++ks)
            S[mt][nt] = __builtin_amdgcn_mfma_f32_16x16x32_bf16(qf[mt][ks], kf[ks], S[mt][nt], 0, 0, 0);
      }
      __builtin_amdgcn_s_setprio(0);

      // softcap (poly) + exp + P write (only last iter needs causal mask)
      const bool domask = (it == iters - 1);
#pragma unroll
      for (int mt = 0; mt < 2; ++mt)
#pragma unroll
        for (int nt = 0; nt < 2; ++nt)
#pragma unroll
          for (int r = 0; r < 4; ++r){
            float s = S[mt][nt][r];
            float w2 = s * s;
            float t = fmaf(w2, A2, A1);
            t = fmaf(w2, t, A0);
            float a = s * t;
            a = fminf(fmaxf(a, -50.f), 50.f);
            float p = __expf(a);
            if (domask){
              int col = k0 + kg * 32 + nt * 16 + cc;
              int row = qrow0 + mt * 16 + qd * 4 + r;
              if (col > row) p = 0.f;
            }
            unsigned u = __builtin_bit_cast(unsigned, p);
            float pt = __builtin_bit_cast(float, u & 0xffff0000u); // truncated bf16 value
            lsum[mt][r] += pt;                                     // l matches stored P exactly
            lP[w][mt * 16 + qd * 4 + r][nt * 16 + cc] = (unsigned short)(u >> 16);
          }

      // counted wait for V(it) -> visible to all after the barrier
      if (it + 1 < iters){
        VM_WAIT(4);      // retire V(it); K(it+1) stays in flight
      } else {
        VM_WAIT(0);      // retire V(it); nothing else outstanding
      }
      barrier_fence();   // all waves' V(it) landed AND all lK[curo] reads done

      // P fragments (A-layout): row = mt*16+cc, keys qd*8..+7 (16B aligned)
      short8 pf[2];
#pragma unroll
      for (int mt = 0; mt < 2; ++mt)
        pf[mt] = *(const short8*)(&lP[w][mt * 16 + cc][qd * 8]);

      // O += P V : B-frag from lV, d-row = dn*16+cc, key chunk = kg*4+qd
      __builtin_amdgcn_s_setprio(1);
#pragma unroll
      for (int dn = 0; dn < 8; ++dn){
        short8 vf = *(const short8*)(lV + ((dn * 16 + cc) * 8 + ((kg * 4 + qd) ^ cx)) * 8);
#pragma unroll
        for (int mt = 0; mt < 2; ++mt)
          o[mt][dn] = __builtin_amdgcn_mfma_f32_16x16x32_bf16(pf[mt], vf, o[mt][dn], 0, 0, 0);
      }
      __builtin_amdgcn_s_setprio(0);

      // all this wave's lV (and lK) ds_reads complete, then barrier: no
      // wave's V(it+1)/K(it+2) LDS writes may land before every read is done
      LGKM_WAIT0;
      barrier_fence();

      // prefetch V(it+1) (consumed after next iter's mid barrier)
      if (it + 1 < iters){
        const unsigned short* gV = gVbp + (k0 + 64);
        unsigned short* dV = lV + w * 2048;
#pragma unroll
        for (int i = 0; i < 4; ++i)
          gll16(gV + (size_t)i * 8 * T_SEQ, dV + i * 512);
      }
      curo ^= 8192;
    }

    // ---- epilogue: reduce l over cc, merge kg partials (additive), store ----
    float lred[2][4];
#pragma unroll
    for (int mt = 0; mt < 2; ++mt)
#pragma unroll
      for (int r = 0; r < 4; ++r){
        float lb = lsum[mt][r];
        lb += __shfl_xor(lb, 1);
        lb += __shfl_xor(lb, 2);
        lb += __shfl_xor(lb, 4);
        lb += __shfl_xor(lb, 8);
        lred[mt][r] = lb;
      }

    __syncthreads();   // full drain; all K/V traffic done before lO overlays
    if (kg == 1){
#pragma unroll
      for (int mt = 0; mt < 2; ++mt){
#pragma unroll
        for (int dn = 0; dn < 8; ++dn)
          *(f32x4*)&lO[(dn * 16 + cc) * 68 + rg * 32 + mt * 16 + qd * 4] = o[mt][dn];
        if (cc == 0){
#pragma unroll
          for (int r = 0; r < 4; ++r)
            lL[rg * 32 + mt * 16 + qd * 4 + r] = lred[mt][r];
        }
      }
    }
    __syncthreads();
    if (kg == 0){
#pragma unroll
      for (int mt = 0; mt < 2; ++mt){
        float inv[4];
#pragma unroll
        for (int r = 0; r < 4; ++r){
          float lt = lred[mt][r] + lL[rg * 32 + mt * 16 + qd * 4 + r];
          inv[r] = __builtin_amdgcn_rcpf(lt);
        }
#pragma unroll
        for (int dn = 0; dn < 8; ++dn){
          f32x4 oo = o[mt][dn] + *(const f32x4*)&lO[(dn * 16 + cc) * 68 + rg * 32 + mt * 16 + qd * 4];
#pragma unroll
          for (int r = 0; r < 4; ++r){
            int row = qrow0 + mt * 16 + qd * 4 + r;
            Yb[(size_t)row * HID + h * HD + dn * 16 + cc] = f2bf(oo[r] * inv[r]);
          }
        }
      }
    }
    __syncthreads();   // lO reads done before next half re-stages K/V
  }
}

extern "C" void kernel_launch(void* const* d_in, const int* in_sizes, int n_in,
                              void* d_out, int out_size, void* d_ws, size_t ws_size,
                              hipStream_t stream) {
  const float* X  = (const float*)d_in[0];
  const float* Wq = (const float*)d_in[1];
  const float* Wk = (const float*)d_in[2];
  const float* Wv = (const float*)d_in[3];
  const float* Wo = (const float*)d_in[4];
  float* out = (float*)d_out;

  unsigned short* ws = (unsigned short*)d_ws;
  unsigned short* Xb = ws;                                   // [T][HID]        16 MiB
  unsigned short* Wt = ws + (size_t)8  * 1024 * 1024;        // [4*2048][2048]  32 MiB
  unsigned short* Qb = ws + (size_t)24 * 1024 * 1024;        // [NH][T][HD]     16 MiB
  unsigned short* Kb = ws + (size_t)32 * 1024 * 1024;        // [NH][T][HD]     16 MiB
  unsigned short* Vt = ws + (size_t)40 * 1024 * 1024;        // [NH][HD][T]     16 MiB
  unsigned short* Yb = Xb;                                   // reuse X region

  conv_x_k<<<8192, 256, 0, stream>>>(X, Xb);
  conv_wt_k<<<dim3(64, 64, 4), dim3(32, 8), 0, stream>>>(Wq, Wk, Wv, Wo, Wt);
  gemm_bt<0, 6144><<<dim3(48, 32), 256, 0, stream>>>(Xb, Wt, Qb, Kb, Vt, nullptr);
  rope_k<<<dim3(1024, NH), 256, 0, stream>>>(Qb, Kb);
  attn_k<<<dim3(512), 256, 0, stream>>>(Qb, Kb, Vt, Yb);
  gemm_bt<1, 2048><<<dim3(16, 32), 256, 0, stream>>>(Yb, Wt + (size_t)6144 * 2048,
                                                     nullptr, nullptr, nullptr, out);
}

// Round 2
// 441.003 us; speedup vs baseline: 1.0119x; 1.0119x over previous
//
#include <hip/hip_runtime.h>
#include <stdint.h>

#define T_SEQ 4096
#define HID   2048
#define NH    16
#define HD    128

typedef __attribute__((ext_vector_type(8))) short short8;
typedef __attribute__((ext_vector_type(4))) short short4v;
typedef __attribute__((ext_vector_type(4))) float f32x4;

typedef __attribute__((address_space(1))) void as1_void;
typedef __attribute__((address_space(3))) void as3_void;

__device__ __forceinline__ unsigned short f2bf(float f){
  unsigned u = __builtin_bit_cast(unsigned, f);
  u += 0x7fffu + ((u >> 16) & 1u);
  return (unsigned short)(u >> 16);
}
__device__ __forceinline__ float bf2f(unsigned short b){
  unsigned u = ((unsigned)b) << 16;
  return __builtin_bit_cast(float, u);
}
// async global->LDS, 16B per lane. LDS side is wave-uniform base + lane*16.
__device__ __forceinline__ void gll16(const void* g, void* l){
  __builtin_amdgcn_global_load_lds((as1_void*)(uintptr_t)g,
                                   (as3_void*)(unsigned)(uintptr_t)l, 16, 0, 0);
}

// counted waits + raw barrier (T3/T4 pattern: never drain vmcnt to 0 mid-loop)
#define VM_WAIT(N)  asm volatile("s_waitcnt vmcnt(" #N ")" ::: "memory")
#define LGKM_WAIT0  asm volatile("s_waitcnt lgkmcnt(0)" ::: "memory")
__device__ __forceinline__ void barrier_fence(){
  asm volatile("" ::: "memory");
  __builtin_amdgcn_s_barrier();
  asm volatile("" ::: "memory");
}

// ---------------- fp32 -> bf16 conversion of X ----------------
__global__ __launch_bounds__(256) void conv_x_k(const float* __restrict__ X,
                                                unsigned short* __restrict__ O){
  int i = (blockIdx.x * 256 + threadIdx.x) * 4;
  float4 v = *(const float4*)(X + i);
  short4v o;
  o[0] = (short)f2bf(v.x); o[1] = (short)f2bf(v.y);
  o[2] = (short)f2bf(v.z); o[3] = (short)f2bf(v.w);
  *(short4v*)(O + i) = o;
}

// ------------- weight transpose + bf16: W[k][n] -> Wt[n][k] -------------
__global__ __launch_bounds__(256) void conv_wt_k(const float* __restrict__ W0,
                                                 const float* __restrict__ W1,
                                                 const float* __restrict__ W2,
                                                 const float* __restrict__ W3,
                                                 unsigned short* __restrict__ Wt){
  const float* W = (blockIdx.z == 0) ? W0 : (blockIdx.z == 1) ? W1
                   : (blockIdx.z == 2) ? W2 : W3;
  unsigned short* out = Wt + (size_t)blockIdx.z * HID * HID;
  __shared__ float tile[32][33];
  const int x = threadIdx.x;       // 0..31
  const int y = threadIdx.y;       // 0..7
  const int k0 = blockIdx.y * 32, n0 = blockIdx.x * 32;
#pragma unroll
  for (int i = 0; i < 4; ++i){
    int r = y * 4 + i;
    tile[r][x] = W[(size_t)(k0 + r) * HID + n0 + x];
  }
  __syncthreads();
#pragma unroll
  for (int i = 0; i < 4; ++i){
    int r = y * 4 + i;
    out[(size_t)(n0 + r) * HID + k0 + x] = f2bf(tile[x][r]);
  }
}

// ---------------- GEMM: C[M][N] = A[M][K=2048] * Bt[N][K]^T ----------------
// 128x128 tile, 4 waves (2x2), BK=64 (32 iters), global_load_lds(16B).
// LDS slot (row, c) holds global chunk c ^ (row&7); fragment read chunk
// (ks*4+qd) ^ (mm&7) -> bank-uniform.
// MODE 0: epilogue scatters bf16 to Q [h][t][d], K [h][t][d], Vt [h][d][t].
// MODE 1: epilogue writes fp32 C row-major [M][NTOT].
template<int MODE, int NTOT>
__global__ __launch_bounds__(256, 3) void gemm_bt(
    const unsigned short* __restrict__ A,
    const unsigned short* __restrict__ Bt,
    unsigned short* __restrict__ Qb,
    unsigned short* __restrict__ Kb,
    unsigned short* __restrict__ Vt,
    float* __restrict__ Cf)
{
  constexpr int K = HID;
  __shared__ __align__(16) unsigned short lA[128 * 64];
  __shared__ __align__(16) unsigned short lB[128 * 64];

  const int tid  = threadIdx.x;
  const int wave = tid >> 6;
  const int lane = tid & 63;
  const int qd   = lane >> 4;
  const int mm   = lane & 15;
  const int m7   = mm & 7;
  const int wm   = wave >> 1;
  const int wn   = wave & 1;
  const int bm   = blockIdx.y * 128;
  const int bn   = blockIdx.x * 128;

  const unsigned short* ga[4];
  const unsigned short* gb[4];
  unsigned short* la[4];
  unsigned short* lbp[4];
#pragma unroll
  for (int i = 0; i < 4; ++i){
    int s0   = (wave * 4 + i) * 64;   // wave-uniform base slot
    int slot = s0 + lane;
    int row  = slot >> 3;
    int kb   = (slot & 7) ^ (row & 7);
    ga[i]  = A  + (size_t)(bm + row) * K + kb * 8;
    gb[i]  = Bt + (size_t)(bn + row) * K + kb * 8;
    la[i]  = lA + s0 * 8;
    lbp[i] = lB + s0 * 8;
  }

  int abase[4], bbase[4];
#pragma unroll
  for (int t = 0; t < 4; ++t){
    abase[t] = (wm * 64 + t * 16 + mm) * 8;
    bbase[t] = (wn * 64 + t * 16 + mm) * 8;
  }

  const f32x4 fzero = {0.f, 0.f, 0.f, 0.f};
  f32x4 acc[4][4];
#pragma unroll
  for (int i = 0; i < 4; ++i)
#pragma unroll
    for (int j = 0; j < 4; ++j) acc[i][j] = fzero;

  for (int k0 = 0; k0 < K; k0 += 64){
    __syncthreads();
#pragma unroll
    for (int i = 0; i < 4; ++i){
      gll16(ga[i] + k0, la[i]);
      gll16(gb[i] + k0, lbp[i]);
    }
    __syncthreads();
#pragma unroll
    for (int ks = 0; ks < 2; ++ks){
      const int co = (ks * 4 + qd) ^ m7;
      short8 af[4], bfv[4];
#pragma unroll
      for (int t = 0; t < 4; ++t) af[t]  = *(const short8*)(lA + (abase[t] + co) * 8);
#pragma unroll
      for (int t = 0; t < 4; ++t) bfv[t] = *(const short8*)(lB + (bbase[t] + co) * 8);
#pragma unroll
      for (int i = 0; i < 4; ++i)
#pragma unroll
        for (int j = 0; j < 4; ++j)
          acc[i][j] = __builtin_amdgcn_mfma_f32_16x16x32_bf16(af[i], bfv[j], acc[i][j], 0, 0, 0);
    }
  }

#pragma unroll
  for (int i = 0; i < 4; ++i){
#pragma unroll
    for (int j = 0; j < 4; ++j){
      const int col = bn + wn * 64 + j * 16 + mm;
#pragma unroll
      for (int r = 0; r < 4; ++r){
        const int row = bm + wm * 64 + i * 16 + qd * 4 + r;
        const float v = acc[i][j][r];
        if (MODE == 0){
          const int sel = col >> 11;
          const int nn  = col & 2047;
          const int h   = nn >> 7;
          const int d   = nn & 127;
          const unsigned short bv = f2bf(v);
          if (sel == 0)      Qb[((size_t)h * T_SEQ + row) * HD + d] = bv;
          else if (sel == 1) Kb[((size_t)h * T_SEQ + row) * HD + d] = bv;
          else               Vt[((size_t)(h * HD + d)) * T_SEQ + row] = bv;
        } else {
          Cf[(size_t)row * NTOT + col] = v;
        }
      }
    }
  }
}

// ---------------- RoPE on Q and K (in place, bf16) ----------------
__global__ __launch_bounds__(256) void rope_k(unsigned short* __restrict__ Qb,
                                              unsigned short* __restrict__ Kb){
  const int j = threadIdx.x & 63;
  const int t = blockIdx.x * 4 + (threadIdx.x >> 6);
  const int h = blockIdx.y;
  const float fr = (float)t * __expf(-(float)j * (9.210340371976184f / 64.f));
  const float cs = cosf(fr), sn = sinf(fr);
  const size_t base = ((size_t)h * T_SEQ + t) * HD;
  {
    float x1 = bf2f(Qb[base + j]), x2 = bf2f(Qb[base + j + 64]);
    Qb[base + j]      = f2bf(x1 * cs - x2 * sn);
    Qb[base + j + 64] = f2bf(x2 * cs + x1 * sn);
  }
  {
    float x1 = bf2f(Kb[base + j]), x2 = bf2f(Kb[base + j + 64]);
    Kb[base + j]      = f2bf(x1 * cs - x2 * sn);
    Kb[base + j + 64] = f2bf(x2 * cs + x1 * sn);
  }
}

// ---------------- flash attention v7 (VALU diet) ----------------
// Block = 4 waves = 2 row-groups (rg, 32 q-rows) x 2 key-groups (kg, 32 keys).
// Paired q-tiles (p, 63-p) -> 65 iters; grid 512 = exactly 2 blocks/CU.
// Pipeline (v6): K double-buffered, V single-buffered, counted vmcnt 8/4,
// 3 barriers/iter (post-PV barrier protects single lV from next prefetch).
// v7 vs v6 (counters: MfmaUtil 22%, VALUBusy 43%, 9.7M lds conflicts ->
// VALU-bound softmax, idle matrix pipe):
//  1. l row-sum via ones-MFMA: acc_l[mt] = mfma(pf[mt], ones) sums the
//     STORED P exactly (reads the same fragment) -> removes per-elem
//     and+add and the epilogue shfl reduce. +2 MFMA/iter on the idle pipe.
//  2. softcap poly folded with log2(e) -> exp2; clamp via fmed3.
//     ~11 -> ~7 VALU ops/elem.
//  3. lP chunk-XOR swizzle (chunk ^= (row>>2)&3): P u16 stores were 8-way
//     bank conflicts (qd cancels: rows 4 apart = 0 mod 32 banks). Write
//     col' = ((col>>3)^qd)*8 + (col&7); read chunk qd^(cc>>2), still one
//     contiguous ds_read_b128.
__global__ __launch_bounds__(256, 2) void attn_k(
    const unsigned short* __restrict__ Qb,   // [NH][T][HD]
    const unsigned short* __restrict__ Kb,   // [NH][T][HD]
    const unsigned short* __restrict__ Vt,   // [NH][HD][T]
    unsigned short* __restrict__ Yb)         // [T][HID]
{
  __shared__ __align__(16) unsigned char smem[57600];
  unsigned short* lK = (unsigned short*)smem;              // 2 x [64 keys][128 d] 32 KB
  unsigned short* lV = (unsigned short*)(smem + 32768);    // [128 d][64 keys]     16 KB
  unsigned short (*lP)[32][32] = (unsigned short(*)[32][32])(smem + 49152); // 8 KB
  float* lL = (float*)(smem + 57344);                      // [64]
  float* lO = (float*)smem;                                // [128 d][68] epilogue overlay

  const int tid  = threadIdx.x;
  const int w    = tid >> 6;
  const int rg   = w >> 1;
  const int kg   = w & 1;
  const int lane = tid & 63;
  const int qd   = lane >> 4;
  const int cc   = lane & 15;
  const int cx   = cc & 7;
  const int r8   = lane >> 3, c7 = lane & 7;

  const int b = blockIdx.x;                 // 512 blocks
  const int h = (b & 7) + 8 * (b >> 8);     // head -> XCD h&7 (L2 locality)
  const int pairP = (b >> 3) & 31;          // 0..31

  // staging source addressing (swizzle on fetch side; slot chunk c holds
  // global chunk c ^ (row&7))
  const int ce  = cc ^ qd;
  const int dlt = (ce & 4) ? -32 : 32;
  const unsigned short* gKbp = Kb + ((size_t)h * T_SEQ + w * 16 + qd) * HD + ce * 8;
  const int cV = c7 ^ r8;
  const unsigned short* gVbp = Vt + ((size_t)h * HD + w * 32 + r8) * T_SEQ + cV * 8;

  // lP store columns (swizzled chunk, per nt); read chunk = qd ^ (cc>>2)
  const int pc0 = (((cc >> 3)    ) ^ qd) * 8 + (cc & 7);   // nt=0
  const int pc1 = (((cc >> 3) + 2) ^ qd) * 8 + (cc & 7);   // nt=1

  const f32x4 fzero = {0.f, 0.f, 0.f, 0.f};
  // 50*tanh(s*SCALE/50)*log2(e) ~= s*(B0 + B1*s^2 + B2*s^4)
  const float B0 = 0.09016844006f;     // 0.0625        * log2(e)
  const float B1 = -4.6962728e-8f;     // -3.2552083e-8 * log2(e)
  const float B2 = 2.9351706e-14f;     // 2.0345052e-14 * log2(e)
  const float CLP = 72.134752f;        // 50 * log2(e)
  short8 onesv;
#pragma unroll
  for (int j = 0; j < 8; ++j) onesv[j] = (short)0x3F80;    // bf16 1.0

#pragma unroll 1
  for (int half = 0; half < 2; ++half){
    const int tp = half ? (63 - pairP) : pairP;
    const int qrow0 = tp * 64 + rg * 32;
    const int iters = tp + 1;

    // prologue: stage K(0) -> buffer 0, V(0) -> lV (4+4 loads per wave)
    {
      unsigned short* dK = lK + w * 2048;
#pragma unroll
      for (int i = 0; i < 4; ++i)
        gll16(gKbp + (size_t)(i * 4) * HD + ((i & 1) ? dlt : 0), dK + i * 512);
      unsigned short* dV = lV + w * 2048;
#pragma unroll
      for (int i = 0; i < 4; ++i)
        gll16(gVbp + (size_t)i * 8 * T_SEQ, dV + i * 512);
    }

    // Q fragments: A-layout, rows qrow0 + mt*16 + cc, d = ks*32 + qd*8
    short8 qf[2][4];
#pragma unroll
    for (int mt = 0; mt < 2; ++mt)
#pragma unroll
      for (int ks = 0; ks < 4; ++ks)
        qf[mt][ks] = *(const short8*)(Qb + ((size_t)h * T_SEQ + qrow0 + mt * 16 + cc) * HD + ks * 32 + qd * 8);

    f32x4 o[2][8];
    f32x4 acc_l[2];
#pragma unroll
    for (int mt = 0; mt < 2; ++mt){
#pragma unroll
      for (int dn = 0; dn < 8; ++dn) o[mt][dn] = fzero;
      acc_l[mt] = fzero;
    }

    int curo = 0;   // current K buffer offset in shorts (0 or 8192)
#pragma unroll 1
    for (int it = 0; it < iters; ++it){
      const int k0 = it * 64;

      // prefetch K(it+1) into the other buffer, then counted wait for K(it)
      if (it + 1 < iters){
        const unsigned short* gK = gKbp + (size_t)(k0 + 64) * HD;
        unsigned short* dK = lK + (curo ^ 8192) + w * 2048;
#pragma unroll
        for (int i = 0; i < 4; ++i)
          gll16(gK + (size_t)(i * 4) * HD + ((i & 1) ? dlt : 0), dK + i * 512);
        VM_WAIT(8);      // retire K(it); V(it)+K(it+1) stay in flight
      } else {
        VM_WAIT(4);      // retire K(it); V(it) stays in flight
      }
      barrier_fence();   // all waves' K(it) landed; lK[curo] valid

      const unsigned short* lKc = lK + curo;

      // S = Q K^T : wave's keys = k0 + kg*32 + nt*16 + cc (nt=0..1)
      f32x4 S[2][2];
#pragma unroll
      for (int mt = 0; mt < 2; ++mt)
#pragma unroll
        for (int nt = 0; nt < 2; ++nt) S[mt][nt] = fzero;
      __builtin_amdgcn_s_setprio(1);
#pragma unroll
      for (int nt = 0; nt < 2; ++nt){
        short8 kf[4];
#pragma unroll
        for (int ks = 0; ks < 4; ++ks)
          kf[ks] = *(const short8*)(lKc + ((kg * 32 + nt * 16 + cc) * 16 + ((ks * 4 + qd) ^ cx)) * 8);
#pragma unroll
        for (int mt = 0; mt < 2; ++mt)
#pragma unroll
          for (int ks = 0; ks < 4; ++ks)
            S[mt][nt] = __builtin_amdgcn_mfma_f32_16x16x32_bf16(qf[mt][ks], kf[ks], S[mt][nt], 0, 0, 0);
      }
      __builtin_amdgcn_s_setprio(0);

      // softcap (poly, log2e folded) + exp2 + P write (mask only last iter)
      const bool domask = (it == iters - 1);
#pragma unroll
      for (int mt = 0; mt < 2; ++mt)
#pragma unroll
        for (int nt = 0; nt < 2; ++nt)
#pragma unroll
          for (int r = 0; r < 4; ++r){
            float s = S[mt][nt][r];
            float w2 = s * s;
            float t = fmaf(w2, B2, B1);
            t = fmaf(w2, t, B0);
            float a = s * t;
            a = __builtin_amdgcn_fmed3f(a, -CLP, CLP);
            float p = __builtin_amdgcn_exp2f(a);
            if (domask){
              int col = k0 + kg * 32 + nt * 16 + cc;
              int row = qrow0 + mt * 16 + qd * 4 + r;
              if (col > row) p = 0.f;
            }
            unsigned u = __builtin_bit_cast(unsigned, p);
            lP[w][mt * 16 + qd * 4 + r][nt ? pc1 : pc0] = (unsigned short)(u >> 16);
          }

      // counted wait for V(it) -> visible to all after the barrier
      if (it + 1 < iters){
        VM_WAIT(4);      // retire V(it); K(it+1) stays in flight
      } else {
        VM_WAIT(0);      // retire V(it); nothing else outstanding
      }
      barrier_fence();   // all waves' V(it) landed AND all lK[curo] reads done

      // P fragments (A-layout): row = mt*16+cc, keys qd*8..+7, chunk-unswizzle
      short8 pf[2];
#pragma unroll
      for (int mt = 0; mt < 2; ++mt)
        pf[mt] = *(const short8*)(&lP[w][mt * 16 + cc][(qd ^ (cc >> 2)) * 8]);

      // O += P V : B-frag from lV, d-row = dn*16+cc, key chunk = kg*4+qd
      // l += P . 1 : ones-MFMA row-sum of the stored P (idle-pipe work)
      __builtin_amdgcn_s_setprio(1);
#pragma unroll
      for (int dn = 0; dn < 8; ++dn){
        short8 vf = *(const short8*)(lV + ((dn * 16 + cc) * 8 + ((kg * 4 + qd) ^ cx)) * 8);
#pragma unroll
        for (int mt = 0; mt < 2; ++mt)
          o[mt][dn] = __builtin_amdgcn_mfma_f32_16x16x32_bf16(pf[mt], vf, o[mt][dn], 0, 0, 0);
      }
#pragma unroll
      for (int mt = 0; mt < 2; ++mt)
        acc_l[mt] = __builtin_amdgcn_mfma_f32_16x16x32_bf16(pf[mt], onesv, acc_l[mt], 0, 0, 0);
      __builtin_amdgcn_s_setprio(0);

      // all this wave's lV (and lK/lP) ds_reads complete, then barrier: no
      // wave's V(it+1)/K(it+2) LDS writes may land before every read is done
      LGKM_WAIT0;
      barrier_fence();

      // prefetch V(it+1) (consumed after next iter's mid barrier)
      if (it + 1 < iters){
        const unsigned short* gV = gVbp + (k0 + 64);
        unsigned short* dV = lV + w * 2048;
#pragma unroll
        for (int i = 0; i < 4; ++i)
          gll16(gV + (size_t)i * 8 * T_SEQ, dV + i * 512);
      }
      curo ^= 8192;
    }

    // ---- epilogue: merge kg partials (additive), normalize, store ----
    // acc_l[mt][r] = row-sum of this wave's keys for q-row mt*16+qd*4+r
    // (identical value in all cc lanes — no shuffle reduce needed)
    __syncthreads();   // full drain; all K/V traffic done before lO overlays
    if (kg == 1){
#pragma unroll
      for (int mt = 0; mt < 2; ++mt){
#pragma unroll
        for (int dn = 0; dn < 8; ++dn)
          *(f32x4*)&lO[(dn * 16 + cc) * 68 + rg * 32 + mt * 16 + qd * 4] = o[mt][dn];
        if (cc == 0){
#pragma unroll
          for (int r = 0; r < 4; ++r)
            lL[rg * 32 + mt * 16 + qd * 4 + r] = acc_l[mt][r];
        }
      }
    }
    __syncthreads();
    if (kg == 0){
#pragma unroll
      for (int mt = 0; mt < 2; ++mt){
        float inv[4];
#pragma unroll
        for (int r = 0; r < 4; ++r){
          float lt = acc_l[mt][r] + lL[rg * 32 + mt * 16 + qd * 4 + r];
          inv[r] = __builtin_amdgcn_rcpf(lt);
        }
#pragma unroll
        for (int dn = 0; dn < 8; ++dn){
          f32x4 oo = o[mt][dn] + *(const f32x4*)&lO[(dn * 16 + cc) * 68 + rg * 32 + mt * 16 + qd * 4];
#pragma unroll
          for (int r = 0; r < 4; ++r){
            int row = qrow0 + mt * 16 + qd * 4 + r;
            Yb[(size_t)row * HID + h * HD + dn * 16 + cc] = f2bf(oo[r] * inv[r]);
          }
        }
      }
    }
    __syncthreads();   // lO reads done before next half re-stages K/V
  }
}

extern "C" void kernel_launch(void* const* d_in, const int* in_sizes, int n_in,
                              void* d_out, int out_size, void* d_ws, size_t ws_size,
                              hipStream_t stream) {
  const float* X  = (const float*)d_in[0];
  const float* Wq = (const float*)d_in[1];
  const float* Wk = (const float*)d_in[2];
  const float* Wv = (const float*)d_in[3];
  const float* Wo = (const float*)d_in[4];
  float* out = (float*)d_out;

  unsigned short* ws = (unsigned short*)d_ws;
  unsigned short* Xb = ws;                                   // [T][HID]        16 MiB
  unsigned short* Wt = ws + (size_t)8  * 1024 * 1024;        // [4*2048][2048]  32 MiB
  unsigned short* Qb = ws + (size_t)24 * 1024 * 1024;        // [NH][T][HD]     16 MiB
  unsigned short* Kb = ws + (size_t)32 * 1024 * 1024;        // [NH][T][HD]     16 MiB
  unsigned short* Vt = ws + (size_t)40 * 1024 * 1024;        // [NH][HD][T]     16 MiB
  unsigned short* Yb = Xb;                                   // reuse X region

  conv_x_k<<<8192, 256, 0, stream>>>(X, Xb);
  conv_wt_k<<<dim3(64, 64, 4), dim3(32, 8), 0, stream>>>(Wq, Wk, Wv, Wo, Wt);
  gemm_bt<0, 6144><<<dim3(48, 32), 256, 0, stream>>>(Xb, Wt, Qb, Kb, Vt, nullptr);
  rope_k<<<dim3(1024, NH), 256, 0, stream>>>(Qb, Kb);
  attn_k<<<dim3(512), 256, 0, stream>>>(Qb, Kb, Vt, Yb);
  gemm_bt<1, 2048><<<dim3(16, 32), 256, 0, stream>>>(Yb, Wt + (size_t)6144 * 2048,
                                                     nullptr, nullptr, nullptr, out);
}

// Round 3
// 425.682 us; speedup vs baseline: 1.0483x; 1.0360x over previous
//
#include <hip/hip_runtime.h>
#include <stdint.h>

#define T_SEQ 4096
#define HID   2048
#define NH    16
#define HD    128

typedef __attribute__((ext_vector_type(8))) short short8;
typedef __attribute__((ext_vector_type(4))) short short4v;
typedef __attribute__((ext_vector_type(4))) float f32x4;

typedef __attribute__((address_space(1))) void as1_void;
typedef __attribute__((address_space(3))) void as3_void;

__device__ __forceinline__ unsigned short f2bf(float f){
  unsigned u = __builtin_bit_cast(unsigned, f);
  u += 0x7fffu + ((u >> 16) & 1u);
  return (unsigned short)(u >> 16);
}
__device__ __forceinline__ float bf2f(unsigned short b){
  unsigned u = ((unsigned)b) << 16;
  return __builtin_bit_cast(float, u);
}
// async global->LDS, 16B per lane. LDS side is wave-uniform base + lane*16.
__device__ __forceinline__ void gll16(const void* g, void* l){
  __builtin_amdgcn_global_load_lds((as1_void*)(uintptr_t)g,
                                   (as3_void*)(unsigned)(uintptr_t)l, 16, 0, 0);
}

#define VM_WAIT0    asm volatile("s_waitcnt vmcnt(0)" ::: "memory")
#define LGKM_WAIT0  asm volatile("s_waitcnt lgkmcnt(0)" ::: "memory")
__device__ __forceinline__ void barrier_fence(){
  asm volatile("" ::: "memory");
  __builtin_amdgcn_s_barrier();
  asm volatile("" ::: "memory");
}

// ---------------- fp32 -> bf16 conversion of X ----------------
__global__ __launch_bounds__(256) void conv_x_k(const float* __restrict__ X,
                                                unsigned short* __restrict__ O){
  int i = (blockIdx.x * 256 + threadIdx.x) * 4;
  float4 v = *(const float4*)(X + i);
  short4v o;
  o[0] = (short)f2bf(v.x); o[1] = (short)f2bf(v.y);
  o[2] = (short)f2bf(v.z); o[3] = (short)f2bf(v.w);
  *(short4v*)(O + i) = o;
}

// ------------- weight transpose + bf16: W[k][n] -> Wt[n][k] -------------
__global__ __launch_bounds__(256) void conv_wt_k(const float* __restrict__ W0,
                                                 const float* __restrict__ W1,
                                                 const float* __restrict__ W2,
                                                 const float* __restrict__ W3,
                                                 unsigned short* __restrict__ Wt){
  const float* W = (blockIdx.z == 0) ? W0 : (blockIdx.z == 1) ? W1
                   : (blockIdx.z == 2) ? W2 : W3;
  unsigned short* out = Wt + (size_t)blockIdx.z * HID * HID;
  __shared__ float tile[32][33];
  const int x = threadIdx.x;       // 0..31
  const int y = threadIdx.y;       // 0..7
  const int k0 = blockIdx.y * 32, n0 = blockIdx.x * 32;
#pragma unroll
  for (int i = 0; i < 4; ++i){
    int r = y * 4 + i;
    tile[r][x] = W[(size_t)(k0 + r) * HID + n0 + x];
  }
  __syncthreads();
#pragma unroll
  for (int i = 0; i < 4; ++i){
    int r = y * 4 + i;
    out[(size_t)(n0 + r) * HID + k0 + x] = f2bf(tile[x][r]);
  }
}

// ---------------- GEMM: C[M][N] = A[M][K=2048] * Bt[N][K]^T ----------------
// 128x128 tile, 4 waves (2x2), BK=64 (32 iters), global_load_lds(16B).
// LDS slot (row, c) holds global chunk c ^ (row&7); fragment read chunk
// (ks*4+qd) ^ (mm&7) -> bank-uniform.
// MODE 0: Q/K blocks scatter bf16 [h][t][d]; V blocks (bn>=4096) transpose
//   the 128x128 tile through LDS (chunk-XOR swizzle) and store Vt [h][d][t]
//   as 256B-contiguous runs (old path: 2B stores 8KB apart, ~64 txn/instr).
// MODE 1: epilogue writes fp32 C row-major [M][NTOT].
template<int MODE, int NTOT>
__global__ __launch_bounds__(256, 3) void gemm_bt(
    const unsigned short* __restrict__ A,
    const unsigned short* __restrict__ Bt,
    unsigned short* __restrict__ Qb,
    unsigned short* __restrict__ Kb,
    unsigned short* __restrict__ Vt,
    float* __restrict__ Cf)
{
  constexpr int K = HID;
  __shared__ __align__(16) unsigned short lAB[16384];   // lA | lB ; reused as lT
  unsigned short* lA = lAB;
  unsigned short* lB = lAB + 8192;

  const int tid  = threadIdx.x;
  const int wave = tid >> 6;
  const int lane = tid & 63;
  const int qd   = lane >> 4;
  const int mm   = lane & 15;
  const int m7   = mm & 7;
  const int wm   = wave >> 1;
  const int wn   = wave & 1;
  const int bm   = blockIdx.y * 128;
  const int bn   = blockIdx.x * 128;

  const unsigned short* ga[4];
  const unsigned short* gb[4];
  unsigned short* la[4];
  unsigned short* lbp[4];
#pragma unroll
  for (int i = 0; i < 4; ++i){
    int s0   = (wave * 4 + i) * 64;   // wave-uniform base slot
    int slot = s0 + lane;
    int row  = slot >> 3;
    int kb   = (slot & 7) ^ (row & 7);
    ga[i]  = A  + (size_t)(bm + row) * K + kb * 8;
    gb[i]  = Bt + (size_t)(bn + row) * K + kb * 8;
    la[i]  = lA + s0 * 8;
    lbp[i] = lB + s0 * 8;
  }

  int abase[4], bbase[4];
#pragma unroll
  for (int t = 0; t < 4; ++t){
    abase[t] = (wm * 64 + t * 16 + mm) * 8;
    bbase[t] = (wn * 64 + t * 16 + mm) * 8;
  }

  const f32x4 fzero = {0.f, 0.f, 0.f, 0.f};
  f32x4 acc[4][4];
#pragma unroll
  for (int i = 0; i < 4; ++i)
#pragma unroll
    for (int j = 0; j < 4; ++j) acc[i][j] = fzero;

  for (int k0 = 0; k0 < K; k0 += 64){
    __syncthreads();
#pragma unroll
    for (int i = 0; i < 4; ++i){
      gll16(ga[i] + k0, la[i]);
      gll16(gb[i] + k0, lbp[i]);
    }
    __syncthreads();
#pragma unroll
    for (int ks = 0; ks < 2; ++ks){
      const int co = (ks * 4 + qd) ^ m7;
      short8 af[4], bfv[4];
#pragma unroll
      for (int t = 0; t < 4; ++t) af[t]  = *(const short8*)(lA + (abase[t] + co) * 8);
#pragma unroll
      for (int t = 0; t < 4; ++t) bfv[t] = *(const short8*)(lB + (bbase[t] + co) * 8);
#pragma unroll
      for (int i = 0; i < 4; ++i)
#pragma unroll
        for (int j = 0; j < 4; ++j)
          acc[i][j] = __builtin_amdgcn_mfma_f32_16x16x32_bf16(af[i], bfv[j], acc[i][j], 0, 0, 0);
    }
  }

  if (MODE == 0 && bn >= 4096){
    // ---- V block: 128x128 tile transpose via LDS, coalesced Vt stores ----
    __syncthreads();   // all lA/lB fragment reads done before overwrite
    unsigned short* lT = lAB;   // [d=128][t-chunks 32][4] u16, chunk XOR swz
#pragma unroll
    for (int i = 0; i < 4; ++i){
#pragma unroll
      for (int j = 0; j < 4; ++j){
        const int d_l   = wn * 64 + j * 16 + mm;
        const int chunk = wm * 16 + i * 4 + qd;     // t_local>>2
        const int ch    = chunk ^ (d_l & 31);
        short4v pk;
#pragma unroll
        for (int r = 0; r < 4; ++r) pk[r] = (short)f2bf(acc[i][j][r]);
        *(short4v*)(lT + d_l * 128 + ch * 4) = pk;
      }
    }
    __syncthreads();
    const int hV = (bn >> 7) - 32;
    const int dd = tid >> 4;          // 0..15
    const int tg = tid & 15;          // 8-t group -> 16B store
#pragma unroll
    for (int p = 0; p < 8; ++p){
      const int d_l = p * 16 + dd;
      const int c0  = (tg * 2)     ^ (d_l & 31);
      const int c1  = (tg * 2 + 1) ^ (d_l & 31);
      short4v lo = *(const short4v*)(lT + d_l * 128 + c0 * 4);
      short4v hi = *(const short4v*)(lT + d_l * 128 + c1 * 4);
      short8 ov;
      ov[0] = lo[0]; ov[1] = lo[1]; ov[2] = lo[2]; ov[3] = lo[3];
      ov[4] = hi[0]; ov[5] = hi[1]; ov[6] = hi[2]; ov[7] = hi[3];
      *(short8*)(Vt + ((size_t)(hV * HD + d_l)) * T_SEQ + bm + tg * 8) = ov;
    }
    return;
  }

#pragma unroll
  for (int i = 0; i < 4; ++i){
#pragma unroll
    for (int j = 0; j < 4; ++j){
      const int col = bn + wn * 64 + j * 16 + mm;
#pragma unroll
      for (int r = 0; r < 4; ++r){
        const int row = bm + wm * 64 + i * 16 + qd * 4 + r;
        const float v = acc[i][j][r];
        if (MODE == 0){
          const int nn  = col & 2047;
          const int h   = nn >> 7;
          const int d   = nn & 127;
          const unsigned short bv = f2bf(v);
          if (col < 2048)      Qb[((size_t)h * T_SEQ + row) * HD + d] = bv;
          else                 Kb[((size_t)h * T_SEQ + row) * HD + d] = bv;
        } else {
          Cf[(size_t)row * NTOT + col] = v;
        }
      }
    }
  }
}

// ---------------- RoPE on Q and K (in place, bf16) ----------------
__global__ __launch_bounds__(256) void rope_k(unsigned short* __restrict__ Qb,
                                              unsigned short* __restrict__ Kb){
  const int j = threadIdx.x & 63;
  const int t = blockIdx.x * 4 + (threadIdx.x >> 6);
  const int h = blockIdx.y;
  const float fr = (float)t * __expf(-(float)j * (9.210340371976184f / 64.f));
  const float cs = cosf(fr), sn = sinf(fr);
  const size_t base = ((size_t)h * T_SEQ + t) * HD;
  {
    float x1 = bf2f(Qb[base + j]), x2 = bf2f(Qb[base + j + 64]);
    Qb[base + j]      = f2bf(x1 * cs - x2 * sn);
    Qb[base + j + 64] = f2bf(x2 * cs + x1 * sn);
  }
  {
    float x1 = bf2f(Kb[base + j]), x2 = bf2f(Kb[base + j + 64]);
    Kb[base + j]      = f2bf(x1 * cs - x2 * sn);
    Kb[base + j + 64] = f2bf(x2 * cs + x1 * sn);
  }
}

// ---------------- flash attention v8 (occupancy 3 blocks/CU) ----------------
// R2 counters: MfmaUtil 23.6, VALUBusy 40.4, Occupancy 20% (2 blocks/CU),
// both pipes idle ~40% of cycles -> latency/barrier-bound at 2 waves/SIMD.
// v8: single-tile blocks (grid 1024 = 16 heads x 64 q-tiles, descending
// iters order for balance), single K buffer, LDS 41216 B -> 3 blocks/CU
// (123.6KB < 160KB) = 3 waves/SIMD. Cross-block TLP covers the per-iter
// staging latency that the (now removed) K-dbuf pipeline failed to hide.
// Block = 4 waves = 2 row-groups (rg, 32 q-rows) x 2 key-groups (kg, 32 keys).
// Head -> XCD pinning: h&7 = b&7 (K+V of 2 heads = 4MB = one XCD L2).
__global__ __launch_bounds__(256, 3) void attn_k(
    const unsigned short* __restrict__ Qb,   // [NH][T][HD]
    const unsigned short* __restrict__ Kb,   // [NH][T][HD]
    const unsigned short* __restrict__ Vt,   // [NH][HD][T]
    unsigned short* __restrict__ Yb)         // [T][HID]
{
  __shared__ __align__(16) unsigned char smem[41216];
  unsigned short* lK = (unsigned short*)smem;              // [64 keys][128 d] 16 KB
  unsigned short* lV = (unsigned short*)(smem + 16384);    // [128 d][64 keys] 16 KB
  unsigned short (*lP)[32][32] = (unsigned short(*)[32][32])(smem + 32768); // 8 KB
  float* lL = (float*)(smem + 40960);                      // [64]
  float* lO = (float*)smem;                                // [128 d][68] epilogue overlay

  const int tid  = threadIdx.x;
  const int w    = tid >> 6;
  const int rg   = w >> 1;
  const int kg   = w & 1;
  const int lane = tid & 63;
  const int qd   = lane >> 4;
  const int cc   = lane & 15;
  const int cx   = cc & 7;
  const int r8   = lane >> 3, c7 = lane & 7;

  const int b  = blockIdx.x;            // 1024 blocks
  const int h  = b & 15;                // head; h&7 = b&7 -> XCD pinned
  const int tp = 63 - (b >> 4);         // big tiles dispatched first
  const int qrow0 = tp * 64 + rg * 32;
  const int iters = tp + 1;

  // staging source addressing (swizzle on fetch side; slot chunk c holds
  // global chunk c ^ (row&7))
  const int ce  = cc ^ qd;
  const int dlt = (ce & 4) ? -32 : 32;
  const unsigned short* gKbp = Kb + ((size_t)h * T_SEQ + w * 16 + qd) * HD + ce * 8;
  const int cV = c7 ^ r8;
  const unsigned short* gVbp = Vt + ((size_t)h * HD + w * 32 + r8) * T_SEQ + cV * 8;

  // lP store columns (swizzled chunk); read chunk = qd ^ (cc>>2)
  const int pc0 = (((cc >> 3)    ) ^ qd) * 8 + (cc & 7);   // nt=0
  const int pc1 = (((cc >> 3) + 2) ^ qd) * 8 + (cc & 7);   // nt=1

  const f32x4 fzero = {0.f, 0.f, 0.f, 0.f};
  // 50*tanh(s*SCALE/50)*log2(e) ~= s*(B0 + B1*s^2 + B2*s^4)
  const float B0 = 0.09016844006f;
  const float B1 = -4.6962728e-8f;
  const float B2 = 2.9351706e-14f;
  const float CLP = 72.134752f;        // 50 * log2(e)
  short8 onesv;
#pragma unroll
  for (int j = 0; j < 8; ++j) onesv[j] = (short)0x3F80;    // bf16 1.0

  // prologue: stage K(0), V(0)
  {
    unsigned short* dK = lK + w * 2048;
#pragma unroll
    for (int i = 0; i < 4; ++i)
      gll16(gKbp + (size_t)(i * 4) * HD + ((i & 1) ? dlt : 0), dK + i * 512);
    unsigned short* dV = lV + w * 2048;
#pragma unroll
    for (int i = 0; i < 4; ++i)
      gll16(gVbp + (size_t)i * 8 * T_SEQ, dV + i * 512);
  }

  // Q fragments: A-layout, rows qrow0 + mt*16 + cc, d = ks*32 + qd*8
  short8 qf[2][4];
#pragma unroll
  for (int mt = 0; mt < 2; ++mt)
#pragma unroll
    for (int ks = 0; ks < 4; ++ks)
      qf[mt][ks] = *(const short8*)(Qb + ((size_t)h * T_SEQ + qrow0 + mt * 16 + cc) * HD + ks * 32 + qd * 8);

  f32x4 o[2][8];
  f32x4 acc_l[2];
#pragma unroll
  for (int mt = 0; mt < 2; ++mt){
#pragma unroll
    for (int dn = 0; dn < 8; ++dn) o[mt][dn] = fzero;
    acc_l[mt] = fzero;
  }

#pragma unroll 1
  for (int it = 0; it < iters; ++it){
    const int k0 = it * 64;
    VM_WAIT0;          // this wave's K(it)/V(it) landed
    barrier_fence();   // all waves' landed; tiles valid

    // S = Q K^T : wave's keys = k0 + kg*32 + nt*16 + cc (nt=0..1)
    f32x4 S[2][2];
#pragma unroll
    for (int mt = 0; mt < 2; ++mt)
#pragma unroll
      for (int nt = 0; nt < 2; ++nt) S[mt][nt] = fzero;
    __builtin_amdgcn_s_setprio(1);
#pragma unroll
    for (int nt = 0; nt < 2; ++nt){
      short8 kf[4];
#pragma unroll
      for (int ks = 0; ks < 4; ++ks)
        kf[ks] = *(const short8*)(lK + ((kg * 32 + nt * 16 + cc) * 16 + ((ks * 4 + qd) ^ cx)) * 8);
#pragma unroll
      for (int mt = 0; mt < 2; ++mt)
#pragma unroll
        for (int ks = 0; ks < 4; ++ks)
          S[mt][nt] = __builtin_amdgcn_mfma_f32_16x16x32_bf16(qf[mt][ks], kf[ks], S[mt][nt], 0, 0, 0);
    }
    __builtin_amdgcn_s_setprio(0);

    // softcap (poly, log2e folded) + exp2 + P write (mask only last iter)
    const bool domask = (it == iters - 1);
#pragma unroll
    for (int mt = 0; mt < 2; ++mt)
#pragma unroll
      for (int nt = 0; nt < 2; ++nt)
#pragma unroll
        for (int r = 0; r < 4; ++r){
          float s = S[mt][nt][r];
          float w2 = s * s;
          float t = fmaf(w2, B2, B1);
          t = fmaf(w2, t, B0);
          float a = s * t;
          a = __builtin_amdgcn_fmed3f(a, -CLP, CLP);
          float p = __builtin_amdgcn_exp2f(a);
          if (domask){
            int col = k0 + kg * 32 + nt * 16 + cc;
            int row = qrow0 + mt * 16 + qd * 4 + r;
            if (col > row) p = 0.f;
          }
          unsigned u = __builtin_bit_cast(unsigned, p);
          lP[w][mt * 16 + qd * 4 + r][nt ? pc1 : pc0] = (unsigned short)(u >> 16);
        }

    // P fragments (A-layout): row = mt*16+cc, keys qd*8..+7 (same-wave RAW
    // through LDS: compiler inserts the lgkmcnt wait on the data dep)
    short8 pf[2];
#pragma unroll
    for (int mt = 0; mt < 2; ++mt)
      pf[mt] = *(const short8*)(&lP[w][mt * 16 + cc][(qd ^ (cc >> 2)) * 8]);

    // O += P V ; l += P . 1 (ones-MFMA row-sum of stored P)
    __builtin_amdgcn_s_setprio(1);
#pragma unroll
    for (int dn = 0; dn < 8; ++dn){
      short8 vf = *(const short8*)(lV + ((dn * 16 + cc) * 8 + ((kg * 4 + qd) ^ cx)) * 8);
#pragma unroll
      for (int mt = 0; mt < 2; ++mt)
        o[mt][dn] = __builtin_amdgcn_mfma_f32_16x16x32_bf16(pf[mt], vf, o[mt][dn], 0, 0, 0);
    }
#pragma unroll
    for (int mt = 0; mt < 2; ++mt)
      acc_l[mt] = __builtin_amdgcn_mfma_f32_16x16x32_bf16(pf[mt], onesv, acc_l[mt], 0, 0, 0);
    __builtin_amdgcn_s_setprio(0);

    // all lK/lV/lP ds_reads of this wave retired, then barrier: next iter's
    // global_load_lds writes must not land before every wave's reads are done
    LGKM_WAIT0;
    barrier_fence();

    if (it + 1 < iters){
      const unsigned short* gK = gKbp + (size_t)(k0 + 64) * HD;
      unsigned short* dK = lK + w * 2048;
#pragma unroll
      for (int i = 0; i < 4; ++i)
        gll16(gK + (size_t)(i * 4) * HD + ((i & 1) ? dlt : 0), dK + i * 512);
      const unsigned short* gV = gVbp + (k0 + 64);
      unsigned short* dV = lV + w * 2048;
#pragma unroll
      for (int i = 0; i < 4; ++i)
        gll16(gV + (size_t)i * 8 * T_SEQ, dV + i * 512);
    }
  }

  // ---- epilogue: merge kg partials (additive), normalize, store ----
  // acc_l[mt][r] = row-sum for q-row mt*16+qd*4+r (same value in all cc)
  __syncthreads();   // all K/V traffic done before lO overlays the region
  if (kg == 1){
#pragma unroll
    for (int mt = 0; mt < 2; ++mt){
#pragma unroll
      for (int dn = 0; dn < 8; ++dn)
        *(f32x4*)&lO[(dn * 16 + cc) * 68 + rg * 32 + mt * 16 + qd * 4] = o[mt][dn];
      if (cc == 0){
#pragma unroll
        for (int r = 0; r < 4; ++r)
          lL[rg * 32 + mt * 16 + qd * 4 + r] = acc_l[mt][r];
      }
    }
  }
  __syncthreads();
  if (kg == 0){
#pragma unroll
    for (int mt = 0; mt < 2; ++mt){
      float inv[4];
#pragma unroll
      for (int r = 0; r < 4; ++r){
        float lt = acc_l[mt][r] + lL[rg * 32 + mt * 16 + qd * 4 + r];
        inv[r] = __builtin_amdgcn_rcpf(lt);
      }
#pragma unroll
      for (int dn = 0; dn < 8; ++dn){
        f32x4 oo = o[mt][dn] + *(const f32x4*)&lO[(dn * 16 + cc) * 68 + rg * 32 + mt * 16 + qd * 4];
#pragma unroll
        for (int r = 0; r < 4; ++r){
          int row = qrow0 + mt * 16 + qd * 4 + r;
          Yb[(size_t)row * HID + h * HD + dn * 16 + cc] = f2bf(oo[r] * inv[r]);
        }
      }
    }
  }
}

extern "C" void kernel_launch(void* const* d_in, const int* in_sizes, int n_in,
                              void* d_out, int out_size, void* d_ws, size_t ws_size,
                              hipStream_t stream) {
  const float* X  = (const float*)d_in[0];
  const float* Wq = (const float*)d_in[1];
  const float* Wk = (const float*)d_in[2];
  const float* Wv = (const float*)d_in[3];
  const float* Wo = (const float*)d_in[4];
  float* out = (float*)d_out;

  unsigned short* ws = (unsigned short*)d_ws;
  unsigned short* Xb = ws;                                   // [T][HID]        16 MiB
  unsigned short* Wt = ws + (size_t)8  * 1024 * 1024;        // [4*2048][2048]  32 MiB
  unsigned short* Qb = ws + (size_t)24 * 1024 * 1024;        // [NH][T][HD]     16 MiB
  unsigned short* Kb = ws + (size_t)32 * 1024 * 1024;        // [NH][T][HD]     16 MiB
  unsigned short* Vt = ws + (size_t)40 * 1024 * 1024;        // [NH][HD][T]     16 MiB
  unsigned short* Yb = Xb;                                   // reuse X region

  conv_x_k<<<8192, 256, 0, stream>>>(X, Xb);
  conv_wt_k<<<dim3(64, 64, 4), dim3(32, 8), 0, stream>>>(Wq, Wk, Wv, Wo, Wt);
  gemm_bt<0, 6144><<<dim3(48, 32), 256, 0, stream>>>(Xb, Wt, Qb, Kb, Vt, nullptr);
  rope_k<<<dim3(1024, NH), 256, 0, stream>>>(Qb, Kb);
  attn_k<<<dim3(1024), 256, 0, stream>>>(Qb, Kb, Vt, Yb);
  gemm_bt<1, 2048><<<dim3(16, 32), 256, 0, stream>>>(Yb, Wt + (size_t)6144 * 2048,
                                                     nullptr, nullptr, nullptr, out);
}